// Round 20
// baseline (166.109 us; speedup 1.0000x reference)
//
#include <hip/hip_runtime.h>
#include <hip/hip_bf16.h>
#include <hip/hip_cooperative_groups.h>
#include <math.h>

namespace cg = cooperative_groups;

// ---------------------------------------------------------------------------
// HybridQuantumKernelNet forward, fp32 throughout.
// x[64,3,250,250] -> conv1(6,5x5,s2,p1)+relu -> [64,6,124,124]
//   -> maxpool2 s1 -> pool1 [64,123,123,6] (CHANNEL-LAST)
//   -> conv2(15,3x3,s2,p1)+relu -> [64,15,62,62] -> maxpool2 s1 -> [64,15,61,61]
//   -> flatten K=55815 -> fc1(120)+relu -> fc2(84)+relu -> fc3(1)
//   -> quantum head cos((z-p)/2)^4 @ kh_w + kh_b -> sigmoid -> [p,1-p]
//
// Ladder notes:
//  r6-r8: conv1 register-window spills at any VGPR cap -> LDS-stage.
//  r9-r14: conv1 LDS + XOR swizzle + prefetch + xs/cs union.
//  r15-r17: zero-LDS conv1 / fc1 reg-prefetch variants spill. Reverted.
//  r19: conv1 2 rows/thread -> 110.3us best.
//  r20 (this): tail merge — fc1_reduce+fc2+final in ONE cooperative kernel
//      (240 blocks, 2 grid.sync()) to remove 2 launch gaps.
// ---------------------------------------------------------------------------

#define KTOT 55815            // 15*61*61
#define KTOT_PAD 55872        // A row stride (alignment only; tail guarded)
#define P1H 123               // pooled1 spatial
#define P2H 61                // pooled2 spatial
#define KC 64                 // fc1 K-chunk (per LDS stage)
#define KSPAN 128             // fc1 K per block (2 chunks)
#define NCHUNK 437            // ceil(55815/128)

// ---------------- Kernel 1: conv1 + relu + maxpool(2,s1), LDS-staged -------
// Tile 32 conv rows x 64 cols. 256 threads = 16 row-pairs x 16 strips(4 cols);
// thread computes conv rows 2q,2q+1 (7-input-row union serves both).
__global__ __launch_bounds__(256) void conv1_pool(
    const float* __restrict__ x, const float* __restrict__ w,
    const float* __restrict__ bias, float* __restrict__ out) {
  __shared__ float smem[6 * 32 * 65];            // 49.92 KB, union xs/cs
  const int b = blockIdx.y;
  const int ytile = blockIdx.x >> 1, xtile = blockIdx.x & 1;
  const int cy_base = 31 * ytile;                // {0,31,62,93}
  const int cx_base = xtile ? 62 : 0;            // EVEN
  const int tid = threadIdx.x;
  const int q = tid >> 4;                        // 0..15 row-pair
  const int st = tid & 15;                       // 0..15 strip of 4 cols
  const int gy0 = 2 * cy_base - 1;               // window top input row
  const int s0 = 2 * cx_base - 4;                // window left col (mult of 4)
  const float* xb = x + b * 187500;
  const int cyA = cy_base + 2 * q;               // conv rows this thread
  const bool vA = (cyA < 124), vB = (cyA + 1 < 124);

  float accA[6][4], accB[6][4];
#pragma unroll
  for (int oc = 0; oc < 6; ++oc) {
    const float bv = bias[oc];
#pragma unroll
    for (int p = 0; p < 4; ++p) { accA[oc][p] = bv; accB[oc][p] = bv; }
  }

  float4 rr[9];
  {
    const float* xc = xb;
#pragma unroll
    for (int s = 0; s < 9; ++s) {
      const int idx = tid + 256 * s;
      float4 v = {0.f, 0.f, 0.f, 0.f};
      if (idx < 67 * 34) {
        const int row = idx / 34, j = idx - row * 34;
        const int gy = gy0 + row, gx = s0 + 4 * j;
        if (gy >= 0 && gy < 250) {
          const float* rp = xc + gy * 250;
          if (gx >= 0 && gx + 3 < 250) {
            v = *reinterpret_cast<const float4*>(rp + gx);
          } else if (gx + 3 >= 0 && gx < 250) {
            v.x = (gx + 0 >= 0 && gx + 0 < 250) ? rp[gx + 0] : 0.f;
            v.y = (gx + 1 >= 0 && gx + 1 < 250) ? rp[gx + 1] : 0.f;
            v.z = (gx + 2 >= 0 && gx + 2 < 250) ? rp[gx + 2] : 0.f;
            v.w = (gx + 3 >= 0 && gx + 3 < 250) ? rp[gx + 3] : 0.f;
          }
        }
      }
      rr[s] = v;
    }
  }

  for (int ic = 0; ic < 3; ++ic) {
    __syncthreads();                             // xs readers done (ic>0)
#pragma unroll
    for (int s = 0; s < 9; ++s) {
      const int idx = tid + 256 * s;
      if (idx < 67 * 34) {
        const int row = idx / 34, j = idx - row * 34;
        const int gj = j ^ ((j >> 3) & 1);
        *reinterpret_cast<float4*>(&smem[row * 136 + 4 * gj]) = rr[s];
      }
    }
    __syncthreads();
    if (ic < 2) {
      const float* xc = xb + (ic + 1) * 62500;
#pragma unroll
      for (int s = 0; s < 9; ++s) {
        const int idx = tid + 256 * s;
        float4 v = {0.f, 0.f, 0.f, 0.f};
        if (idx < 67 * 34) {
          const int row = idx / 34, j = idx - row * 34;
          const int gy = gy0 + row, gx = s0 + 4 * j;
          if (gy >= 0 && gy < 250) {
            const float* rp = xc + gy * 250;
            if (gx >= 0 && gx + 3 < 250) {
              v = *reinterpret_cast<const float4*>(rp + gx);
            } else if (gx + 3 >= 0 && gx < 250) {
              v.x = (gx + 0 >= 0 && gx + 0 < 250) ? rp[gx + 0] : 0.f;
              v.y = (gx + 1 >= 0 && gx + 1 < 250) ? rp[gx + 1] : 0.f;
              v.z = (gx + 2 >= 0 && gx + 2 < 250) ? rp[gx + 2] : 0.f;
              v.w = (gx + 3 >= 0 && gx + 3 < 250) ? rp[gx + 3] : 0.f;
            }
          }
        }
        rr[s] = v;
      }
    }
    // compute: 7 input rows serve conv rows 2q (ky=ii) and 2q+1 (ky=ii-2)
#pragma unroll
    for (int ii = 0; ii < 7; ++ii) {
      const int row = 4 * q + ii;
      float r16[16];
#pragma unroll
      for (int qq = 0; qq < 4; ++qq) {
        const int c = 2 * st + qq;
        const int gc = c ^ ((c >> 3) & 1);
        const float4 v =
            *reinterpret_cast<const float4*>(&smem[row * 136 + 4 * gc]);
        r16[4 * qq + 0] = v.x; r16[4 * qq + 1] = v.y;
        r16[4 * qq + 2] = v.z; r16[4 * qq + 3] = v.w;
      }
      if (ii <= 4) {                             // conv row 2q, ky=ii
#pragma unroll
        for (int oc = 0; oc < 6; ++oc) {
          const float* wp = w + oc * 75 + ic * 25 + ii * 5;
#pragma unroll
          for (int kx = 0; kx < 5; ++kx) {
            const float wv = wp[kx];             // wave-uniform s_load
#pragma unroll
            for (int p = 0; p < 4; ++p)
              accA[oc][p] = fmaf(r16[2 * p + 3 + kx], wv, accA[oc][p]);
          }
        }
      }
      if (ii >= 2) {                             // conv row 2q+1, ky=ii-2
#pragma unroll
        for (int oc = 0; oc < 6; ++oc) {
          const float* wp = w + oc * 75 + ic * 25 + (ii - 2) * 5;
#pragma unroll
          for (int kx = 0; kx < 5; ++kx) {
            const float wv = wp[kx];
#pragma unroll
            for (int p = 0; p < 4; ++p)
              accB[oc][p] = fmaf(r16[2 * p + 3 + kx], wv, accB[oc][p]);
          }
        }
      }
    }
  }

  __syncthreads();                               // xs fully dead -> reuse as cs
#pragma unroll
  for (int oc = 0; oc < 6; ++oc)
#pragma unroll
    for (int p = 0; p < 4; ++p) {
      smem[(oc * 32 + 2 * q + 0) * 65 + 4 * st + p] =
          vA ? fmaxf(accA[oc][p], 0.f) : 0.f;
      smem[(oc * 32 + 2 * q + 1) * 65 + 4 * st + p] =
          vB ? fmaxf(accB[oc][p], 0.f) : 0.f;
    }
  __syncthreads();

  // Pool phase: 31x63 pooled positions per tile, channel-last stores.
  for (int idx = tid; idx < 31 * 63; idx += 256) {
    const int pyl = idx / 63, pxl = idx % 63;
    const int py = cy_base + pyl;
    const int px = cx_base + pxl;
    if (py > 122) continue;
    if (xtile == 1 && (pxl == 0 || px > 122)) continue;
    float* ob = out + ((size_t)(b * P1H + py) * P1H + px) * 6;
    float v[6];
#pragma unroll
    for (int oc = 0; oc < 6; ++oc) {
      const float* c0 = &smem[(oc * 32 + pyl) * 65];
      const float* c1 = &smem[(oc * 32 + pyl + 1) * 65];
      v[oc] = fmaxf(fmaxf(c0[pxl], c0[pxl + 1]), fmaxf(c1[pxl], c1[pxl + 1]));
    }
    float2 o0 = {v[0], v[1]}, o1 = {v[2], v[3]}, o2 = {v[4], v[5]};
    *reinterpret_cast<float2*>(ob + 0) = o0;
    *reinterpret_cast<float2*>(ob + 2) = o1;
    *reinterpret_cast<float2*>(ob + 4) = o2;
  }
}

// ---------------- Kernel 2: conv2 + relu + maxpool(2,s1) fused -------------
__global__ __launch_bounds__(256, 2) void conv2_pool(
    const float* __restrict__ in, const float* __restrict__ w,
    const float* __restrict__ bias, float* __restrict__ A) {
  __shared__ float cs[15][16][16];
  const int b = blockIdx.y;
  const int ty = blockIdx.x / 5, tx = blockIdx.x % 5;
  const int py0 = ty * 15, px0 = tx * 15;
  const int tid = threadIdx.x;
  const int cyl = tid >> 4, cxl = tid & 15;
  const int cy = py0 + cyl, cx = px0 + cxl;
  const float* ib = in + (size_t)b * (P1H * P1H * 6);
  const bool cv = (cy < 62) && (cx < 62);
  const int iy0 = 2 * cy - 1, ix0 = 2 * cx - 1;

  float rin[54];                                  // layout [ky][kx][ic]
#pragma unroll
  for (int ky = 0; ky < 3; ++ky) {
    const int iy = iy0 + ky;
#pragma unroll
    for (int kx = 0; kx < 3; ++kx) {
      const int ix = ix0 + kx;
      const int e = (ky * 3 + kx) * 6;
      const bool ok = cv && (iy >= 0) && (iy < P1H) && (ix >= 0) && (ix < P1H);
      if (ok) {
        const float* p = ib + ((size_t)iy * P1H + ix) * 6;
        const float2 v0 = *reinterpret_cast<const float2*>(p + 0);
        const float2 v1 = *reinterpret_cast<const float2*>(p + 2);
        const float2 v2 = *reinterpret_cast<const float2*>(p + 4);
        rin[e + 0] = v0.x; rin[e + 1] = v0.y; rin[e + 2] = v1.x;
        rin[e + 3] = v1.y; rin[e + 4] = v2.x; rin[e + 5] = v2.y;
      } else {
        rin[e + 0] = 0.f; rin[e + 1] = 0.f; rin[e + 2] = 0.f;
        rin[e + 3] = 0.f; rin[e + 4] = 0.f; rin[e + 5] = 0.f;
      }
    }
  }
#pragma unroll
  for (int oc = 0; oc < 15; ++oc) {
    float a = bias[oc];
#pragma unroll
    for (int ic = 0; ic < 6; ++ic)
#pragma unroll
      for (int ky = 0; ky < 3; ++ky)
#pragma unroll
        for (int kx = 0; kx < 3; ++kx)
          a = fmaf(rin[(ky * 3 + kx) * 6 + ic],
                   w[oc * 54 + ic * 9 + ky * 3 + kx], a);
    cs[oc][cyl][cxl] = fmaxf(a, 0.f);
  }
  __syncthreads();
  if (tid < 225) {
    const int pyl = tid / 15, pxl = tid % 15;
    const int py = py0 + pyl, px = px0 + pxl;
    if (py < P2H && px < P2H) {
      float* ob = A + (size_t)b * KTOT_PAD;
#pragma unroll
      for (int oc = 0; oc < 15; ++oc) {
        const float v = fmaxf(fmaxf(cs[oc][pyl][pxl], cs[oc][pyl][pxl + 1]),
                              fmaxf(cs[oc][pyl + 1][pxl], cs[oc][pyl + 1][pxl + 1]));
        ob[oc * (P2H * P2H) + py * P2H + px] = v;
      }
    }
  }
}

// ---------------- Kernel 3: fc1 split-K partials, register-tiled -----------
// r12 config verbatim — NO register carrying across barriers (r16/r17).
__global__ __launch_bounds__(256) void fc1_partial(
    const float* __restrict__ A, const float* __restrict__ W,
    float* __restrict__ part) {
  __shared__ float As[64 * KC];                  // 16 KB
  __shared__ float Ws[120 * KC];                 // 30.7 KB
  const int tid = threadIdx.x;
  const int chunk = blockIdx.x;
  const int lane = tid & 63;
  const int wave = __builtin_amdgcn_readfirstlane(tid >> 6);
  const int mg = lane >> 3, ng = lane & 7;
  const int n0 = wave * 32;

  float acc[8][4];
#pragma unroll
  for (int r = 0; r < 8; ++r)
#pragma unroll
    for (int s = 0; s < 4; ++s) acc[r][s] = 0.0f;

  for (int half = 0; half < 2; ++half) {
    const int k0 = chunk * KSPAN + half * KC;
    const bool full = (k0 + KC <= KTOT);
    __syncthreads();                             // prev readers done

    for (int idx = tid; idx < 64 * 16; idx += 256) {
      const int m = idx >> 4, j = idx & 15;
      const int kg = k0 + 4 * j;
      float4 v;
      if (full || kg + 3 < KTOT) {
        v = *reinterpret_cast<const float4*>(A + (size_t)m * KTOT_PAD + kg);
      } else {
        v.x = (kg + 0 < KTOT) ? A[(size_t)m * KTOT_PAD + kg + 0] : 0.f;
        v.y = (kg + 1 < KTOT) ? A[(size_t)m * KTOT_PAD + kg + 1] : 0.f;
        v.z = (kg + 2 < KTOT) ? A[(size_t)m * KTOT_PAD + kg + 2] : 0.f;
        v.w = (kg + 3 < KTOT) ? A[(size_t)m * KTOT_PAD + kg + 3] : 0.f;
      }
      const int slot = (j & 8) | ((j & 7) ^ ((m >> 3) & 7));
      *reinterpret_cast<float4*>(&As[m * KC + 4 * slot]) = v;
    }
    if (full) {
      for (int idx = tid; idx < 120 * KC; idx += 256) {
        const int n = idx >> 6, k = idx & 63;
        const int j = k >> 2, q = k & 3;
        const int slot = (j & 8) | ((j & 7) ^ ((n >> 2) & 7));
        Ws[n * KC + 4 * slot + q] = W[(size_t)n * KTOT + k0 + k];
      }
    } else {
      for (int idx = tid; idx < 120 * KC; idx += 256) {
        const int n = idx >> 6, k = idx & 63;
        const int j = k >> 2, q = k & 3;
        const int slot = (j & 8) | ((j & 7) ^ ((n >> 2) & 7));
        const int kg = k0 + k;
        Ws[n * KC + 4 * slot + q] = (kg < KTOT) ? W[(size_t)n * KTOT + kg] : 0.f;
      }
    }
    __syncthreads();

    const float* Abase = As + mg * 8 * KC;
    const float* Wbase = Ws + (n0 + ng * 4) * KC;
#pragma unroll
    for (int k4 = 0; k4 < KC / 4; ++k4) {
      const int sA = 4 * ((k4 & 8) | ((k4 & 7) ^ mg));
      const int sW = 4 * ((k4 & 8) | ((k4 & 7) ^ ng));
      float4 a[8], wv[4];
#pragma unroll
      for (int r = 0; r < 8; ++r)
        a[r] = *reinterpret_cast<const float4*>(Abase + r * KC + sA);
#pragma unroll
      for (int s = 0; s < 4; ++s)
        wv[s] = *reinterpret_cast<const float4*>(Wbase + s * KC + sW);
#pragma unroll
      for (int r = 0; r < 8; ++r)
#pragma unroll
        for (int s = 0; s < 4; ++s) {
          float t = acc[r][s];
          t = fmaf(a[r].x, wv[s].x, t);
          t = fmaf(a[r].y, wv[s].y, t);
          t = fmaf(a[r].z, wv[s].z, t);
          t = fmaf(a[r].w, wv[s].w, t);
          acc[r][s] = t;
        }
    }
  }

  if (n0 + 4 * ng <= 116) {
    float* pb = part + (size_t)chunk * 7680 + n0 + 4 * ng;
#pragma unroll
    for (int r = 0; r < 8; ++r) {
      const float4 v = {acc[r][0], acc[r][1], acc[r][2], acc[r][3]};
      *reinterpret_cast<float4*>(pb + (mg * 8 + r) * 120) = v;
    }
  }
}

// ---------------- Kernel 4: COOPERATIVE tail: reduce + fc2 + head ----------
// Grid 240 x 256. Phase1: all blocks reduce partials -> h1 (32 t's each).
// grid.sync. Phase2: blocks 0..20 do fc2 (wave j = blk*4+wave). grid.sync.
// Phase3: block 0 lanes 0..63 do fc3 + quantum head + sigmoid.
// LDS: red 1KB + hs 31KB = 32KB -> 5 blocks/CU capacity (240 << 1280).
__global__ __launch_bounds__(256) void tail_kernel(
    const float* __restrict__ part, const float* __restrict__ b1,
    const float* __restrict__ W2, const float* __restrict__ b2,
    const float* __restrict__ w3, const float* __restrict__ b3,
    const float* __restrict__ proto, const float* __restrict__ khw,
    const float* __restrict__ khb, float* __restrict__ h1,
    float* __restrict__ h2, float* __restrict__ out) {
  cg::grid_group grid = cg::this_grid();
  __shared__ float red[8][32];
  __shared__ float hs[64][121];
  const int tid = threadIdx.x;

  // Phase 1: fc1 reduce + bias + relu
  {
    const int q = tid >> 5, l = tid & 31;
    const int t = blockIdx.x * 32 + l;           // 240*32 = 7680
    float s = 0.0f;
    for (int c = q; c < NCHUNK; c += 8) s += part[(size_t)c * 7680 + t];
    red[q][l] = s;
    __syncthreads();
    if (q == 0) {
      float v = red[0][l] + red[1][l] + red[2][l] + red[3][l] +
                red[4][l] + red[5][l] + red[6][l] + red[7][l] + b1[t % 120];
      h1[t] = fmaxf(v, 0.0f);
    }
  }
  grid.sync();

  // Phase 2: fc2 + relu on blocks 0..20
  if (blockIdx.x < 21) {
    for (int i = tid; i < 7680; i += 256) hs[i / 120][i % 120] = h1[i];
    __syncthreads();
    const int m = tid & 63;
    const int j = blockIdx.x * 4 + __builtin_amdgcn_readfirstlane(tid >> 6);
    const float* wj = W2 + j * 120;
    float a = b2[j];
    for (int k = 0; k < 120; ++k) a = fmaf(hs[m][k], wj[k], a);
    h2[m * 84 + j] = fmaxf(a, 0.0f);
  }
  grid.sync();

  // Phase 3: fc3 + quantum head + sigmoid on block 0
  if (blockIdx.x == 0 && tid < 64) {
    const float* h = h2 + tid * 84;
    float z = b3[0];
    for (int k = 0; k < 84; ++k) z = fmaf(h[k], w3[k], z);
    float logit = khb[0];
#pragma unroll
    for (int p = 0; p < 10; ++p) {
      const float c = cosf((z - proto[p]) * 0.5f);
      const float c2 = c * c;
      logit = fmaf(c2 * c2, khw[p], logit);
    }
    const float pr = 1.0f / (1.0f + expf(-logit));
    out[tid * 2 + 0] = pr;
    out[tid * 2 + 1] = 1.0f - pr;
  }
}

// ---------------------------------------------------------------------------
extern "C" void kernel_launch(void* const* d_in, const int* in_sizes, int n_in,
                              void* d_out, int out_size, void* d_ws, size_t ws_size,
                              hipStream_t stream) {
  const float* x    = (const float*)d_in[0];
  const float* w1   = (const float*)d_in[1];
  const float* b1   = (const float*)d_in[2];
  const float* w2   = (const float*)d_in[3];
  const float* b2   = (const float*)d_in[4];
  const float* fw1  = (const float*)d_in[5];
  const float* fb1  = (const float*)d_in[6];
  const float* fw2  = (const float*)d_in[7];
  const float* fb2  = (const float*)d_in[8];
  const float* fw3  = (const float*)d_in[9];
  const float* fb3  = (const float*)d_in[10];
  const float* prot = (const float*)d_in[11];
  const float* khw  = (const float*)d_in[12];
  const float* khb  = (const float*)d_in[13];
  float* out = (float*)d_out;

  float* ws = (float*)d_ws;
  // pool1 (dead after conv2) is aliased by fc1 partials (written after).
  float* pool1 = ws;                           // 64*123*123*6 = 5,809,536 f
  float* part  = ws;                           // 437*7680     = 3,356,160 f (alias)
  float* A     = ws + 5809536;                 // 64*55872     = 3,575,808 f
  float* h1    = A + 3575808;                  // 7680 f
  float* h2    = h1 + 7680;                    // 5376 f

  conv1_pool <<<dim3(8, 64), 256, 0, stream>>>(x, w1, b1, pool1);
  conv2_pool <<<dim3(25, 64), 256, 0, stream>>>(pool1, w2, b2, A);
  fc1_partial<<<dim3(NCHUNK), 256, 0, stream>>>(A, fw1, part);

  void* targs[] = {(void*)&part, (void*)&fb1, (void*)&fw2, (void*)&fb2,
                   (void*)&fw3, (void*)&fb3, (void*)&prot, (void*)&khw,
                   (void*)&khb, (void*)&h1, (void*)&h2, (void*)&out};
  hipLaunchCooperativeKernel((const void*)tail_kernel, dim3(240), dim3(256),
                             targs, 0, stream);
}

// Round 21
// 109.725 us; speedup vs baseline: 1.5139x; 1.5139x over previous
//
#include <hip/hip_runtime.h>
#include <hip/hip_bf16.h>
#include <math.h>

// ---------------------------------------------------------------------------
// HybridQuantumKernelNet forward, fp32 throughout.
// x[64,3,250,250] -> conv1(6,5x5,s2,p1)+relu -> [64,6,124,124]
//   -> maxpool2 s1 -> pool1 [64,123,123,6] (CHANNEL-LAST)
//   -> conv2(15,3x3,s2,p1)+relu -> [64,15,62,62] -> maxpool2 s1 -> [64,15,61,61]
//   -> flatten K=55815 -> fc1(120)+relu -> fc2(84)+relu -> fc3(1)
//   -> quantum head cos((z-p)/2)^4 @ kh_w + kh_b -> sigmoid -> [p,1-p]
//
// Ladder notes (final state = r19, 110.3us):
//  r6-r8: conv1 register-window spills at any VGPR cap -> LDS-stage.
//  r9-r14: conv1 LDS + XOR bank swizzle + reg prefetch + xs/cs union.
//  r15-r17: zero-LDS conv1 / fc1 reg-prefetch variants spill. Reverted.
//  r19: conv1 2 conv-rows/thread (7-input-row union) -> best.
//  r20: cooperative tail merge REGRESSED: grid.sync() ~30us each on MI355X
//      (cross-XCD rendezvous) >> 2-3us launch gaps. Reverted here.
// ---------------------------------------------------------------------------

#define KTOT 55815            // 15*61*61
#define KTOT_PAD 55872        // A row stride (alignment only; tail guarded)
#define P1H 123               // pooled1 spatial
#define P2H 61                // pooled2 spatial
#define KC 64                 // fc1 K-chunk (per LDS stage)
#define KSPAN 128             // fc1 K per block (2 chunks)
#define NCHUNK 437            // ceil(55815/128)

// ---------------- Kernel 1: conv1 + relu + maxpool(2,s1), LDS-staged -------
// Tile 32 conv rows x 64 cols. 256 threads = 16 row-pairs x 16 strips(4 cols);
// thread computes conv rows 2q,2q+1 (7-input-row union serves both).
__global__ __launch_bounds__(256) void conv1_pool(
    const float* __restrict__ x, const float* __restrict__ w,
    const float* __restrict__ bias, float* __restrict__ out) {
  __shared__ float smem[6 * 32 * 65];            // 49.92 KB, union xs/cs
  const int b = blockIdx.y;
  const int ytile = blockIdx.x >> 1, xtile = blockIdx.x & 1;
  const int cy_base = 31 * ytile;                // {0,31,62,93}
  const int cx_base = xtile ? 62 : 0;            // EVEN
  const int tid = threadIdx.x;
  const int q = tid >> 4;                        // 0..15 row-pair
  const int st = tid & 15;                       // 0..15 strip of 4 cols
  const int gy0 = 2 * cy_base - 1;               // window top input row
  const int s0 = 2 * cx_base - 4;                // window left col (mult of 4)
  const float* xb = x + b * 187500;
  const int cyA = cy_base + 2 * q;               // conv rows this thread
  const bool vA = (cyA < 124), vB = (cyA + 1 < 124);

  float accA[6][4], accB[6][4];
#pragma unroll
  for (int oc = 0; oc < 6; ++oc) {
    const float bv = bias[oc];
#pragma unroll
    for (int p = 0; p < 4; ++p) { accA[oc][p] = bv; accB[oc][p] = bv; }
  }

  float4 rr[9];
  {
    const float* xc = xb;
#pragma unroll
    for (int s = 0; s < 9; ++s) {
      const int idx = tid + 256 * s;
      float4 v = {0.f, 0.f, 0.f, 0.f};
      if (idx < 67 * 34) {
        const int row = idx / 34, j = idx - row * 34;
        const int gy = gy0 + row, gx = s0 + 4 * j;
        if (gy >= 0 && gy < 250) {
          const float* rp = xc + gy * 250;
          if (gx >= 0 && gx + 3 < 250) {
            v = *reinterpret_cast<const float4*>(rp + gx);
          } else if (gx + 3 >= 0 && gx < 250) {
            v.x = (gx + 0 >= 0 && gx + 0 < 250) ? rp[gx + 0] : 0.f;
            v.y = (gx + 1 >= 0 && gx + 1 < 250) ? rp[gx + 1] : 0.f;
            v.z = (gx + 2 >= 0 && gx + 2 < 250) ? rp[gx + 2] : 0.f;
            v.w = (gx + 3 >= 0 && gx + 3 < 250) ? rp[gx + 3] : 0.f;
          }
        }
      }
      rr[s] = v;
    }
  }

  for (int ic = 0; ic < 3; ++ic) {
    __syncthreads();                             // xs readers done (ic>0)
#pragma unroll
    for (int s = 0; s < 9; ++s) {
      const int idx = tid + 256 * s;
      if (idx < 67 * 34) {
        const int row = idx / 34, j = idx - row * 34;
        const int gj = j ^ ((j >> 3) & 1);
        *reinterpret_cast<float4*>(&smem[row * 136 + 4 * gj]) = rr[s];
      }
    }
    __syncthreads();
    if (ic < 2) {
      const float* xc = xb + (ic + 1) * 62500;
#pragma unroll
      for (int s = 0; s < 9; ++s) {
        const int idx = tid + 256 * s;
        float4 v = {0.f, 0.f, 0.f, 0.f};
        if (idx < 67 * 34) {
          const int row = idx / 34, j = idx - row * 34;
          const int gy = gy0 + row, gx = s0 + 4 * j;
          if (gy >= 0 && gy < 250) {
            const float* rp = xc + gy * 250;
            if (gx >= 0 && gx + 3 < 250) {
              v = *reinterpret_cast<const float4*>(rp + gx);
            } else if (gx + 3 >= 0 && gx < 250) {
              v.x = (gx + 0 >= 0 && gx + 0 < 250) ? rp[gx + 0] : 0.f;
              v.y = (gx + 1 >= 0 && gx + 1 < 250) ? rp[gx + 1] : 0.f;
              v.z = (gx + 2 >= 0 && gx + 2 < 250) ? rp[gx + 2] : 0.f;
              v.w = (gx + 3 >= 0 && gx + 3 < 250) ? rp[gx + 3] : 0.f;
            }
          }
        }
        rr[s] = v;
      }
    }
    // compute: 7 input rows serve conv rows 2q (ky=ii) and 2q+1 (ky=ii-2)
#pragma unroll
    for (int ii = 0; ii < 7; ++ii) {
      const int row = 4 * q + ii;
      float r16[16];
#pragma unroll
      for (int qq = 0; qq < 4; ++qq) {
        const int c = 2 * st + qq;
        const int gc = c ^ ((c >> 3) & 1);
        const float4 v =
            *reinterpret_cast<const float4*>(&smem[row * 136 + 4 * gc]);
        r16[4 * qq + 0] = v.x; r16[4 * qq + 1] = v.y;
        r16[4 * qq + 2] = v.z; r16[4 * qq + 3] = v.w;
      }
      if (ii <= 4) {                             // conv row 2q, ky=ii
#pragma unroll
        for (int oc = 0; oc < 6; ++oc) {
          const float* wp = w + oc * 75 + ic * 25 + ii * 5;
#pragma unroll
          for (int kx = 0; kx < 5; ++kx) {
            const float wv = wp[kx];             // wave-uniform s_load
#pragma unroll
            for (int p = 0; p < 4; ++p)
              accA[oc][p] = fmaf(r16[2 * p + 3 + kx], wv, accA[oc][p]);
          }
        }
      }
      if (ii >= 2) {                             // conv row 2q+1, ky=ii-2
#pragma unroll
        for (int oc = 0; oc < 6; ++oc) {
          const float* wp = w + oc * 75 + ic * 25 + (ii - 2) * 5;
#pragma unroll
          for (int kx = 0; kx < 5; ++kx) {
            const float wv = wp[kx];
#pragma unroll
            for (int p = 0; p < 4; ++p)
              accB[oc][p] = fmaf(r16[2 * p + 3 + kx], wv, accB[oc][p]);
          }
        }
      }
    }
  }

  __syncthreads();                               // xs fully dead -> reuse as cs
#pragma unroll
  for (int oc = 0; oc < 6; ++oc)
#pragma unroll
    for (int p = 0; p < 4; ++p) {
      smem[(oc * 32 + 2 * q + 0) * 65 + 4 * st + p] =
          vA ? fmaxf(accA[oc][p], 0.f) : 0.f;
      smem[(oc * 32 + 2 * q + 1) * 65 + 4 * st + p] =
          vB ? fmaxf(accB[oc][p], 0.f) : 0.f;
    }
  __syncthreads();

  // Pool phase: 31x63 pooled positions per tile, channel-last stores.
  for (int idx = tid; idx < 31 * 63; idx += 256) {
    const int pyl = idx / 63, pxl = idx % 63;
    const int py = cy_base + pyl;
    const int px = cx_base + pxl;
    if (py > 122) continue;
    if (xtile == 1 && (pxl == 0 || px > 122)) continue;
    float* ob = out + ((size_t)(b * P1H + py) * P1H + px) * 6;
    float v[6];
#pragma unroll
    for (int oc = 0; oc < 6; ++oc) {
      const float* c0 = &smem[(oc * 32 + pyl) * 65];
      const float* c1 = &smem[(oc * 32 + pyl + 1) * 65];
      v[oc] = fmaxf(fmaxf(c0[pxl], c0[pxl + 1]), fmaxf(c1[pxl], c1[pxl + 1]));
    }
    float2 o0 = {v[0], v[1]}, o1 = {v[2], v[3]}, o2 = {v[4], v[5]};
    *reinterpret_cast<float2*>(ob + 0) = o0;
    *reinterpret_cast<float2*>(ob + 2) = o1;
    *reinterpret_cast<float2*>(ob + 4) = o2;
  }
}

// ---------------- Kernel 2: conv2 + relu + maxpool(2,s1) fused -------------
__global__ __launch_bounds__(256, 2) void conv2_pool(
    const float* __restrict__ in, const float* __restrict__ w,
    const float* __restrict__ bias, float* __restrict__ A) {
  __shared__ float cs[15][16][16];
  const int b = blockIdx.y;
  const int ty = blockIdx.x / 5, tx = blockIdx.x % 5;
  const int py0 = ty * 15, px0 = tx * 15;
  const int tid = threadIdx.x;
  const int cyl = tid >> 4, cxl = tid & 15;
  const int cy = py0 + cyl, cx = px0 + cxl;
  const float* ib = in + (size_t)b * (P1H * P1H * 6);
  const bool cv = (cy < 62) && (cx < 62);
  const int iy0 = 2 * cy - 1, ix0 = 2 * cx - 1;

  float rin[54];                                  // layout [ky][kx][ic]
#pragma unroll
  for (int ky = 0; ky < 3; ++ky) {
    const int iy = iy0 + ky;
#pragma unroll
    for (int kx = 0; kx < 3; ++kx) {
      const int ix = ix0 + kx;
      const int e = (ky * 3 + kx) * 6;
      const bool ok = cv && (iy >= 0) && (iy < P1H) && (ix >= 0) && (ix < P1H);
      if (ok) {
        const float* p = ib + ((size_t)iy * P1H + ix) * 6;
        const float2 v0 = *reinterpret_cast<const float2*>(p + 0);
        const float2 v1 = *reinterpret_cast<const float2*>(p + 2);
        const float2 v2 = *reinterpret_cast<const float2*>(p + 4);
        rin[e + 0] = v0.x; rin[e + 1] = v0.y; rin[e + 2] = v1.x;
        rin[e + 3] = v1.y; rin[e + 4] = v2.x; rin[e + 5] = v2.y;
      } else {
        rin[e + 0] = 0.f; rin[e + 1] = 0.f; rin[e + 2] = 0.f;
        rin[e + 3] = 0.f; rin[e + 4] = 0.f; rin[e + 5] = 0.f;
      }
    }
  }
#pragma unroll
  for (int oc = 0; oc < 15; ++oc) {
    float a = bias[oc];
#pragma unroll
    for (int ic = 0; ic < 6; ++ic)
#pragma unroll
      for (int ky = 0; ky < 3; ++ky)
#pragma unroll
        for (int kx = 0; kx < 3; ++kx)
          a = fmaf(rin[(ky * 3 + kx) * 6 + ic],
                   w[oc * 54 + ic * 9 + ky * 3 + kx], a);
    cs[oc][cyl][cxl] = fmaxf(a, 0.f);
  }
  __syncthreads();
  if (tid < 225) {
    const int pyl = tid / 15, pxl = tid % 15;
    const int py = py0 + pyl, px = px0 + pxl;
    if (py < P2H && px < P2H) {
      float* ob = A + (size_t)b * KTOT_PAD;
#pragma unroll
      for (int oc = 0; oc < 15; ++oc) {
        const float v = fmaxf(fmaxf(cs[oc][pyl][pxl], cs[oc][pyl][pxl + 1]),
                              fmaxf(cs[oc][pyl + 1][pxl], cs[oc][pyl + 1][pxl + 1]));
        ob[oc * (P2H * P2H) + py * P2H + px] = v;
      }
    }
  }
}

// ---------------- Kernel 3: fc1 split-K partials, register-tiled -----------
// r12 config verbatim — NO register carrying across barriers (r16/r17).
__global__ __launch_bounds__(256) void fc1_partial(
    const float* __restrict__ A, const float* __restrict__ W,
    float* __restrict__ part) {
  __shared__ float As[64 * KC];                  // 16 KB
  __shared__ float Ws[120 * KC];                 // 30.7 KB
  const int tid = threadIdx.x;
  const int chunk = blockIdx.x;
  const int lane = tid & 63;
  const int wave = __builtin_amdgcn_readfirstlane(tid >> 6);
  const int mg = lane >> 3, ng = lane & 7;
  const int n0 = wave * 32;

  float acc[8][4];
#pragma unroll
  for (int r = 0; r < 8; ++r)
#pragma unroll
    for (int s = 0; s < 4; ++s) acc[r][s] = 0.0f;

  for (int half = 0; half < 2; ++half) {
    const int k0 = chunk * KSPAN + half * KC;
    const bool full = (k0 + KC <= KTOT);
    __syncthreads();                             // prev readers done

    for (int idx = tid; idx < 64 * 16; idx += 256) {
      const int m = idx >> 4, j = idx & 15;
      const int kg = k0 + 4 * j;
      float4 v;
      if (full || kg + 3 < KTOT) {
        v = *reinterpret_cast<const float4*>(A + (size_t)m * KTOT_PAD + kg);
      } else {
        v.x = (kg + 0 < KTOT) ? A[(size_t)m * KTOT_PAD + kg + 0] : 0.f;
        v.y = (kg + 1 < KTOT) ? A[(size_t)m * KTOT_PAD + kg + 1] : 0.f;
        v.z = (kg + 2 < KTOT) ? A[(size_t)m * KTOT_PAD + kg + 2] : 0.f;
        v.w = (kg + 3 < KTOT) ? A[(size_t)m * KTOT_PAD + kg + 3] : 0.f;
      }
      const int slot = (j & 8) | ((j & 7) ^ ((m >> 3) & 7));
      *reinterpret_cast<float4*>(&As[m * KC + 4 * slot]) = v;
    }
    if (full) {
      for (int idx = tid; idx < 120 * KC; idx += 256) {
        const int n = idx >> 6, k = idx & 63;
        const int j = k >> 2, q = k & 3;
        const int slot = (j & 8) | ((j & 7) ^ ((n >> 2) & 7));
        Ws[n * KC + 4 * slot + q] = W[(size_t)n * KTOT + k0 + k];
      }
    } else {
      for (int idx = tid; idx < 120 * KC; idx += 256) {
        const int n = idx >> 6, k = idx & 63;
        const int j = k >> 2, q = k & 3;
        const int slot = (j & 8) | ((j & 7) ^ ((n >> 2) & 7));
        const int kg = k0 + k;
        Ws[n * KC + 4 * slot + q] = (kg < KTOT) ? W[(size_t)n * KTOT + kg] : 0.f;
      }
    }
    __syncthreads();

    const float* Abase = As + mg * 8 * KC;
    const float* Wbase = Ws + (n0 + ng * 4) * KC;
#pragma unroll
    for (int k4 = 0; k4 < KC / 4; ++k4) {
      const int sA = 4 * ((k4 & 8) | ((k4 & 7) ^ mg));
      const int sW = 4 * ((k4 & 8) | ((k4 & 7) ^ ng));
      float4 a[8], wv[4];
#pragma unroll
      for (int r = 0; r < 8; ++r)
        a[r] = *reinterpret_cast<const float4*>(Abase + r * KC + sA);
#pragma unroll
      for (int s = 0; s < 4; ++s)
        wv[s] = *reinterpret_cast<const float4*>(Wbase + s * KC + sW);
#pragma unroll
      for (int r = 0; r < 8; ++r)
#pragma unroll
        for (int s = 0; s < 4; ++s) {
          float t = acc[r][s];
          t = fmaf(a[r].x, wv[s].x, t);
          t = fmaf(a[r].y, wv[s].y, t);
          t = fmaf(a[r].z, wv[s].z, t);
          t = fmaf(a[r].w, wv[s].w, t);
          acc[r][s] = t;
        }
    }
  }

  if (n0 + 4 * ng <= 116) {
    float* pb = part + (size_t)chunk * 7680 + n0 + 4 * ng;
#pragma unroll
    for (int r = 0; r < 8; ++r) {
      const float4 v = {acc[r][0], acc[r][1], acc[r][2], acc[r][3]};
      *reinterpret_cast<float4*>(pb + (mg * 8 + r) * 120) = v;
    }
  }
}

// ---------------- Kernel 4: reduce partials + bias + relu ------------------
__global__ __launch_bounds__(256) void fc1_reduce(
    const float* __restrict__ part, const float* __restrict__ bias,
    float* __restrict__ h1) {
  __shared__ float red[8][32];
  const int tid = threadIdx.x;
  const int q = tid >> 5, l = tid & 31;
  const int t = blockIdx.x * 32 + l;   // 240*32 = 7680
  float s = 0.0f;
  for (int c = q; c < NCHUNK; c += 8) s += part[(size_t)c * 7680 + t];
  red[q][l] = s;
  __syncthreads();
  if (q == 0) {
    float v = red[0][l] + red[1][l] + red[2][l] + red[3][l] +
              red[4][l] + red[5][l] + red[6][l] + red[7][l] + bias[t % 120];
    h1[t] = fmaxf(v, 0.0f);
  }
}

// ---------------- Kernel 5: fc2 + relu (21 blocks, 1 column/wave) ----------
__global__ __launch_bounds__(256) void fc2_kernel(
    const float* __restrict__ h1, const float* __restrict__ W,
    const float* __restrict__ bias, float* __restrict__ h2) {
  __shared__ float hs[64][121];
  const int tid = threadIdx.x;
  for (int i = tid; i < 7680; i += 256) hs[i / 120][i % 120] = h1[i];
  __syncthreads();
  const int m = tid & 63;
  const int j = blockIdx.x * 4 + __builtin_amdgcn_readfirstlane(tid >> 6);
  const float* wj = W + j * 120;
  float a = bias[j];
  for (int k = 0; k < 120; ++k) a = fmaf(hs[m][k], wj[k], a);
  h2[m * 84 + j] = fmaxf(a, 0.0f);
}

// ---------------- Kernel 6: fc3 + quantum kernel head + sigmoid ------------
__global__ void final_kernel(
    const float* __restrict__ h2, const float* __restrict__ w3,
    const float* __restrict__ b3, const float* __restrict__ proto,
    const float* __restrict__ khw, const float* __restrict__ khb,
    float* __restrict__ out) {
  const int m = threadIdx.x;  // 64 lanes
  const float* h = h2 + m * 84;
  float z = b3[0];
  for (int k = 0; k < 84; ++k) z = fmaf(h[k], w3[k], z);
  float logit = khb[0];
#pragma unroll
  for (int p = 0; p < 10; ++p) {
    const float c = cosf((z - proto[p]) * 0.5f);
    const float c2 = c * c;
    logit = fmaf(c2 * c2, khw[p], logit);
  }
  const float pr = 1.0f / (1.0f + expf(-logit));
  out[m * 2 + 0] = pr;
  out[m * 2 + 1] = 1.0f - pr;
}

// ---------------------------------------------------------------------------
extern "C" void kernel_launch(void* const* d_in, const int* in_sizes, int n_in,
                              void* d_out, int out_size, void* d_ws, size_t ws_size,
                              hipStream_t stream) {
  const float* x    = (const float*)d_in[0];
  const float* w1   = (const float*)d_in[1];
  const float* b1   = (const float*)d_in[2];
  const float* w2   = (const float*)d_in[3];
  const float* b2   = (const float*)d_in[4];
  const float* fw1  = (const float*)d_in[5];
  const float* fb1  = (const float*)d_in[6];
  const float* fw2  = (const float*)d_in[7];
  const float* fb2  = (const float*)d_in[8];
  const float* fw3  = (const float*)d_in[9];
  const float* fb3  = (const float*)d_in[10];
  const float* prot = (const float*)d_in[11];
  const float* khw  = (const float*)d_in[12];
  const float* khb  = (const float*)d_in[13];
  float* out = (float*)d_out;

  float* ws = (float*)d_ws;
  // pool1 (dead after conv2) is aliased by fc1 partials (written after).
  float* pool1 = ws;                           // 64*123*123*6 = 5,809,536 f
  float* part  = ws;                           // 437*7680     = 3,356,160 f (alias)
  float* A     = ws + 5809536;                 // 64*55872     = 3,575,808 f
  float* h1    = A + 3575808;                  // 7680 f
  float* h2    = h1 + 7680;                    // 5376 f

  conv1_pool <<<dim3(8, 64), 256, 0, stream>>>(x, w1, b1, pool1);
  conv2_pool <<<dim3(25, 64), 256, 0, stream>>>(pool1, w2, b2, A);
  fc1_partial<<<dim3(NCHUNK), 256, 0, stream>>>(A, fw1, part);
  fc1_reduce <<<dim3(240), 256, 0, stream>>>(part, fb1, h1);
  fc2_kernel <<<dim3(21), 256, 0, stream>>>(h1, fw2, fb2, h2);
  final_kernel<<<dim3(1), 64, 0, stream>>>(h2, fw3, fb3, prot, khw, khb, out);
}

// Round 22
// 109.438 us; speedup vs baseline: 1.5178x; 1.0026x over previous
//
#include <hip/hip_runtime.h>
#include <hip/hip_bf16.h>
#include <math.h>

// ---------------------------------------------------------------------------
// HybridQuantumKernelNet forward, fp32 throughout.
// x[64,3,250,250] -> conv1(6,5x5,s2,p1)+relu -> [64,6,124,124]
//   -> maxpool2 s1 -> pool1 [64,123,123,6] (CHANNEL-LAST)
//   -> conv2(15,3x3,s2,p1)+relu -> [64,15,62,62] -> maxpool2 s1 -> [64,15,61,61]
//   -> flatten K=55815 -> fc1(120)+relu -> fc2(84)+relu -> fc3(1)
//   -> quantum head cos((z-p)/2)^4 @ kh_w + kh_b -> sigmoid -> [p,1-p]
//
// Ladder notes:
//  r6-r8: conv1 register-window spills at any VGPR cap -> LDS-stage.
//  r9-r14: conv1 LDS + XOR bank swizzle + reg prefetch + xs/cs union.
//  r15-r17: zero-LDS conv1 / fc1 reg-prefetch variants spill. Reverted.
//  r19: conv1 2 conv-rows/thread (7-input-row union) -> 110us band.
//  r20: cooperative tail merge REGRESSED (grid.sync ~30us on MI355X).
//  r22 (this): fc1 KSPAN 128->256 (4 KC=64 stages/block, inner code
//      unchanged): part traffic 26.8->13.4MB, A re-reads halved,
//      fc1_reduce input halved. Inverse of r13's failed direction.
// ---------------------------------------------------------------------------

#define KTOT 55815            // 15*61*61
#define KTOT_PAD 55872        // A row stride (alignment only; tail guarded)
#define P1H 123               // pooled1 spatial
#define P2H 61                // pooled2 spatial
#define KC 64                 // fc1 K-chunk (per LDS stage)
#define KSPAN 256             // fc1 K per block (4 chunks)
#define NCHUNK 219            // ceil(55815/256)

// ---------------- Kernel 1: conv1 + relu + maxpool(2,s1), LDS-staged -------
// Tile 32 conv rows x 64 cols. 256 threads = 16 row-pairs x 16 strips(4 cols);
// thread computes conv rows 2q,2q+1 (7-input-row union serves both).
__global__ __launch_bounds__(256) void conv1_pool(
    const float* __restrict__ x, const float* __restrict__ w,
    const float* __restrict__ bias, float* __restrict__ out) {
  __shared__ float smem[6 * 32 * 65];            // 49.92 KB, union xs/cs
  const int b = blockIdx.y;
  const int ytile = blockIdx.x >> 1, xtile = blockIdx.x & 1;
  const int cy_base = 31 * ytile;                // {0,31,62,93}
  const int cx_base = xtile ? 62 : 0;            // EVEN
  const int tid = threadIdx.x;
  const int q = tid >> 4;                        // 0..15 row-pair
  const int st = tid & 15;                       // 0..15 strip of 4 cols
  const int gy0 = 2 * cy_base - 1;               // window top input row
  const int s0 = 2 * cx_base - 4;                // window left col (mult of 4)
  const float* xb = x + b * 187500;
  const int cyA = cy_base + 2 * q;               // conv rows this thread
  const bool vA = (cyA < 124), vB = (cyA + 1 < 124);

  float accA[6][4], accB[6][4];
#pragma unroll
  for (int oc = 0; oc < 6; ++oc) {
    const float bv = bias[oc];
#pragma unroll
    for (int p = 0; p < 4; ++p) { accA[oc][p] = bv; accB[oc][p] = bv; }
  }

  float4 rr[9];
  {
    const float* xc = xb;
#pragma unroll
    for (int s = 0; s < 9; ++s) {
      const int idx = tid + 256 * s;
      float4 v = {0.f, 0.f, 0.f, 0.f};
      if (idx < 67 * 34) {
        const int row = idx / 34, j = idx - row * 34;
        const int gy = gy0 + row, gx = s0 + 4 * j;
        if (gy >= 0 && gy < 250) {
          const float* rp = xc + gy * 250;
          if (gx >= 0 && gx + 3 < 250) {
            v = *reinterpret_cast<const float4*>(rp + gx);
          } else if (gx + 3 >= 0 && gx < 250) {
            v.x = (gx + 0 >= 0 && gx + 0 < 250) ? rp[gx + 0] : 0.f;
            v.y = (gx + 1 >= 0 && gx + 1 < 250) ? rp[gx + 1] : 0.f;
            v.z = (gx + 2 >= 0 && gx + 2 < 250) ? rp[gx + 2] : 0.f;
            v.w = (gx + 3 >= 0 && gx + 3 < 250) ? rp[gx + 3] : 0.f;
          }
        }
      }
      rr[s] = v;
    }
  }

  for (int ic = 0; ic < 3; ++ic) {
    __syncthreads();                             // xs readers done (ic>0)
#pragma unroll
    for (int s = 0; s < 9; ++s) {
      const int idx = tid + 256 * s;
      if (idx < 67 * 34) {
        const int row = idx / 34, j = idx - row * 34;
        const int gj = j ^ ((j >> 3) & 1);
        *reinterpret_cast<float4*>(&smem[row * 136 + 4 * gj]) = rr[s];
      }
    }
    __syncthreads();
    if (ic < 2) {
      const float* xc = xb + (ic + 1) * 62500;
#pragma unroll
      for (int s = 0; s < 9; ++s) {
        const int idx = tid + 256 * s;
        float4 v = {0.f, 0.f, 0.f, 0.f};
        if (idx < 67 * 34) {
          const int row = idx / 34, j = idx - row * 34;
          const int gy = gy0 + row, gx = s0 + 4 * j;
          if (gy >= 0 && gy < 250) {
            const float* rp = xc + gy * 250;
            if (gx >= 0 && gx + 3 < 250) {
              v = *reinterpret_cast<const float4*>(rp + gx);
            } else if (gx + 3 >= 0 && gx < 250) {
              v.x = (gx + 0 >= 0 && gx + 0 < 250) ? rp[gx + 0] : 0.f;
              v.y = (gx + 1 >= 0 && gx + 1 < 250) ? rp[gx + 1] : 0.f;
              v.z = (gx + 2 >= 0 && gx + 2 < 250) ? rp[gx + 2] : 0.f;
              v.w = (gx + 3 >= 0 && gx + 3 < 250) ? rp[gx + 3] : 0.f;
            }
          }
        }
        rr[s] = v;
      }
    }
    // compute: 7 input rows serve conv rows 2q (ky=ii) and 2q+1 (ky=ii-2)
#pragma unroll
    for (int ii = 0; ii < 7; ++ii) {
      const int row = 4 * q + ii;
      float r16[16];
#pragma unroll
      for (int qq = 0; qq < 4; ++qq) {
        const int c = 2 * st + qq;
        const int gc = c ^ ((c >> 3) & 1);
        const float4 v =
            *reinterpret_cast<const float4*>(&smem[row * 136 + 4 * gc]);
        r16[4 * qq + 0] = v.x; r16[4 * qq + 1] = v.y;
        r16[4 * qq + 2] = v.z; r16[4 * qq + 3] = v.w;
      }
      if (ii <= 4) {                             // conv row 2q, ky=ii
#pragma unroll
        for (int oc = 0; oc < 6; ++oc) {
          const float* wp = w + oc * 75 + ic * 25 + ii * 5;
#pragma unroll
          for (int kx = 0; kx < 5; ++kx) {
            const float wv = wp[kx];             // wave-uniform s_load
#pragma unroll
            for (int p = 0; p < 4; ++p)
              accA[oc][p] = fmaf(r16[2 * p + 3 + kx], wv, accA[oc][p]);
          }
        }
      }
      if (ii >= 2) {                             // conv row 2q+1, ky=ii-2
#pragma unroll
        for (int oc = 0; oc < 6; ++oc) {
          const float* wp = w + oc * 75 + ic * 25 + (ii - 2) * 5;
#pragma unroll
          for (int kx = 0; kx < 5; ++kx) {
            const float wv = wp[kx];
#pragma unroll
            for (int p = 0; p < 4; ++p)
              accB[oc][p] = fmaf(r16[2 * p + 3 + kx], wv, accB[oc][p]);
          }
        }
      }
    }
  }

  __syncthreads();                               // xs fully dead -> reuse as cs
#pragma unroll
  for (int oc = 0; oc < 6; ++oc)
#pragma unroll
    for (int p = 0; p < 4; ++p) {
      smem[(oc * 32 + 2 * q + 0) * 65 + 4 * st + p] =
          vA ? fmaxf(accA[oc][p], 0.f) : 0.f;
      smem[(oc * 32 + 2 * q + 1) * 65 + 4 * st + p] =
          vB ? fmaxf(accB[oc][p], 0.f) : 0.f;
    }
  __syncthreads();

  // Pool phase: 31x63 pooled positions per tile, channel-last stores.
  for (int idx = tid; idx < 31 * 63; idx += 256) {
    const int pyl = idx / 63, pxl = idx % 63;
    const int py = cy_base + pyl;
    const int px = cx_base + pxl;
    if (py > 122) continue;
    if (xtile == 1 && (pxl == 0 || px > 122)) continue;
    float* ob = out + ((size_t)(b * P1H + py) * P1H + px) * 6;
    float v[6];
#pragma unroll
    for (int oc = 0; oc < 6; ++oc) {
      const float* c0 = &smem[(oc * 32 + pyl) * 65];
      const float* c1 = &smem[(oc * 32 + pyl + 1) * 65];
      v[oc] = fmaxf(fmaxf(c0[pxl], c0[pxl + 1]), fmaxf(c1[pxl], c1[pxl + 1]));
    }
    float2 o0 = {v[0], v[1]}, o1 = {v[2], v[3]}, o2 = {v[4], v[5]};
    *reinterpret_cast<float2*>(ob + 0) = o0;
    *reinterpret_cast<float2*>(ob + 2) = o1;
    *reinterpret_cast<float2*>(ob + 4) = o2;
  }
}

// ---------------- Kernel 2: conv2 + relu + maxpool(2,s1) fused -------------
__global__ __launch_bounds__(256, 2) void conv2_pool(
    const float* __restrict__ in, const float* __restrict__ w,
    const float* __restrict__ bias, float* __restrict__ A) {
  __shared__ float cs[15][16][16];
  const int b = blockIdx.y;
  const int ty = blockIdx.x / 5, tx = blockIdx.x % 5;
  const int py0 = ty * 15, px0 = tx * 15;
  const int tid = threadIdx.x;
  const int cyl = tid >> 4, cxl = tid & 15;
  const int cy = py0 + cyl, cx = px0 + cxl;
  const float* ib = in + (size_t)b * (P1H * P1H * 6);
  const bool cv = (cy < 62) && (cx < 62);
  const int iy0 = 2 * cy - 1, ix0 = 2 * cx - 1;

  float rin[54];                                  // layout [ky][kx][ic]
#pragma unroll
  for (int ky = 0; ky < 3; ++ky) {
    const int iy = iy0 + ky;
#pragma unroll
    for (int kx = 0; kx < 3; ++kx) {
      const int ix = ix0 + kx;
      const int e = (ky * 3 + kx) * 6;
      const bool ok = cv && (iy >= 0) && (iy < P1H) && (ix >= 0) && (ix < P1H);
      if (ok) {
        const float* p = ib + ((size_t)iy * P1H + ix) * 6;
        const float2 v0 = *reinterpret_cast<const float2*>(p + 0);
        const float2 v1 = *reinterpret_cast<const float2*>(p + 2);
        const float2 v2 = *reinterpret_cast<const float2*>(p + 4);
        rin[e + 0] = v0.x; rin[e + 1] = v0.y; rin[e + 2] = v1.x;
        rin[e + 3] = v1.y; rin[e + 4] = v2.x; rin[e + 5] = v2.y;
      } else {
        rin[e + 0] = 0.f; rin[e + 1] = 0.f; rin[e + 2] = 0.f;
        rin[e + 3] = 0.f; rin[e + 4] = 0.f; rin[e + 5] = 0.f;
      }
    }
  }
#pragma unroll
  for (int oc = 0; oc < 15; ++oc) {
    float a = bias[oc];
#pragma unroll
    for (int ic = 0; ic < 6; ++ic)
#pragma unroll
      for (int ky = 0; ky < 3; ++ky)
#pragma unroll
        for (int kx = 0; kx < 3; ++kx)
          a = fmaf(rin[(ky * 3 + kx) * 6 + ic],
                   w[oc * 54 + ic * 9 + ky * 3 + kx], a);
    cs[oc][cyl][cxl] = fmaxf(a, 0.f);
  }
  __syncthreads();
  if (tid < 225) {
    const int pyl = tid / 15, pxl = tid % 15;
    const int py = py0 + pyl, px = px0 + pxl;
    if (py < P2H && px < P2H) {
      float* ob = A + (size_t)b * KTOT_PAD;
#pragma unroll
      for (int oc = 0; oc < 15; ++oc) {
        const float v = fmaxf(fmaxf(cs[oc][pyl][pxl], cs[oc][pyl][pxl + 1]),
                              fmaxf(cs[oc][pyl + 1][pxl], cs[oc][pyl + 1][pxl + 1]));
        ob[oc * (P2H * P2H) + py * P2H + px] = v;
      }
    }
  }
}

// ---------------- Kernel 3: fc1 split-K partials, register-tiled -----------
// Block = K-span 256 as 4 sequential LDS chunks of KC=64 (inner code is the
// r12 stage/compute verbatim; NO cross-barrier register carrying).
__global__ __launch_bounds__(256) void fc1_partial(
    const float* __restrict__ A, const float* __restrict__ W,
    float* __restrict__ part) {
  __shared__ float As[64 * KC];                  // 16 KB
  __shared__ float Ws[120 * KC];                 // 30.7 KB
  const int tid = threadIdx.x;
  const int chunk = blockIdx.x;
  const int lane = tid & 63;
  const int wave = __builtin_amdgcn_readfirstlane(tid >> 6);
  const int mg = lane >> 3, ng = lane & 7;
  const int n0 = wave * 32;

  float acc[8][4];
#pragma unroll
  for (int r = 0; r < 8; ++r)
#pragma unroll
    for (int s = 0; s < 4; ++s) acc[r][s] = 0.0f;

  for (int half = 0; half < 4; ++half) {
    const int k0 = chunk * KSPAN + half * KC;
    const bool full = (k0 + KC <= KTOT);
    __syncthreads();                             // prev readers done

    for (int idx = tid; idx < 64 * 16; idx += 256) {
      const int m = idx >> 4, j = idx & 15;
      const int kg = k0 + 4 * j;
      float4 v;
      if (full || kg + 3 < KTOT) {
        v = *reinterpret_cast<const float4*>(A + (size_t)m * KTOT_PAD + kg);
      } else {
        v.x = (kg + 0 < KTOT) ? A[(size_t)m * KTOT_PAD + kg + 0] : 0.f;
        v.y = (kg + 1 < KTOT) ? A[(size_t)m * KTOT_PAD + kg + 1] : 0.f;
        v.z = (kg + 2 < KTOT) ? A[(size_t)m * KTOT_PAD + kg + 2] : 0.f;
        v.w = (kg + 3 < KTOT) ? A[(size_t)m * KTOT_PAD + kg + 3] : 0.f;
      }
      const int slot = (j & 8) | ((j & 7) ^ ((m >> 3) & 7));
      *reinterpret_cast<float4*>(&As[m * KC + 4 * slot]) = v;
    }
    if (full) {
      for (int idx = tid; idx < 120 * KC; idx += 256) {
        const int n = idx >> 6, k = idx & 63;
        const int j = k >> 2, q = k & 3;
        const int slot = (j & 8) | ((j & 7) ^ ((n >> 2) & 7));
        Ws[n * KC + 4 * slot + q] = W[(size_t)n * KTOT + k0 + k];
      }
    } else {
      for (int idx = tid; idx < 120 * KC; idx += 256) {
        const int n = idx >> 6, k = idx & 63;
        const int j = k >> 2, q = k & 3;
        const int slot = (j & 8) | ((j & 7) ^ ((n >> 2) & 7));
        const int kg = k0 + k;
        Ws[n * KC + 4 * slot + q] = (kg < KTOT) ? W[(size_t)n * KTOT + kg] : 0.f;
      }
    }
    __syncthreads();

    const float* Abase = As + mg * 8 * KC;
    const float* Wbase = Ws + (n0 + ng * 4) * KC;
#pragma unroll
    for (int k4 = 0; k4 < KC / 4; ++k4) {
      const int sA = 4 * ((k4 & 8) | ((k4 & 7) ^ mg));
      const int sW = 4 * ((k4 & 8) | ((k4 & 7) ^ ng));
      float4 a[8], wv[4];
#pragma unroll
      for (int r = 0; r < 8; ++r)
        a[r] = *reinterpret_cast<const float4*>(Abase + r * KC + sA);
#pragma unroll
      for (int s = 0; s < 4; ++s)
        wv[s] = *reinterpret_cast<const float4*>(Wbase + s * KC + sW);
#pragma unroll
      for (int r = 0; r < 8; ++r)
#pragma unroll
        for (int s = 0; s < 4; ++s) {
          float t = acc[r][s];
          t = fmaf(a[r].x, wv[s].x, t);
          t = fmaf(a[r].y, wv[s].y, t);
          t = fmaf(a[r].z, wv[s].z, t);
          t = fmaf(a[r].w, wv[s].w, t);
          acc[r][s] = t;
        }
    }
  }

  if (n0 + 4 * ng <= 116) {
    float* pb = part + (size_t)chunk * 7680 + n0 + 4 * ng;
#pragma unroll
    for (int r = 0; r < 8; ++r) {
      const float4 v = {acc[r][0], acc[r][1], acc[r][2], acc[r][3]};
      *reinterpret_cast<float4*>(pb + (mg * 8 + r) * 120) = v;
    }
  }
}

// ---------------- Kernel 4: reduce partials + bias + relu ------------------
__global__ __launch_bounds__(256) void fc1_reduce(
    const float* __restrict__ part, const float* __restrict__ bias,
    float* __restrict__ h1) {
  __shared__ float red[8][32];
  const int tid = threadIdx.x;
  const int q = tid >> 5, l = tid & 31;
  const int t = blockIdx.x * 32 + l;   // 240*32 = 7680
  float s = 0.0f;
  for (int c = q; c < NCHUNK; c += 8) s += part[(size_t)c * 7680 + t];
  red[q][l] = s;
  __syncthreads();
  if (q == 0) {
    float v = red[0][l] + red[1][l] + red[2][l] + red[3][l] +
              red[4][l] + red[5][l] + red[6][l] + red[7][l] + bias[t % 120];
    h1[t] = fmaxf(v, 0.0f);
  }
}

// ---------------- Kernel 5: fc2 + relu (21 blocks, 1 column/wave) ----------
__global__ __launch_bounds__(256) void fc2_kernel(
    const float* __restrict__ h1, const float* __restrict__ W,
    const float* __restrict__ bias, float* __restrict__ h2) {
  __shared__ float hs[64][121];
  const int tid = threadIdx.x;
  for (int i = tid; i < 7680; i += 256) hs[i / 120][i % 120] = h1[i];
  __syncthreads();
  const int m = tid & 63;
  const int j = blockIdx.x * 4 + __builtin_amdgcn_readfirstlane(tid >> 6);
  const float* wj = W + j * 120;
  float a = bias[j];
  for (int k = 0; k < 120; ++k) a = fmaf(hs[m][k], wj[k], a);
  h2[m * 84 + j] = fmaxf(a, 0.0f);
}

// ---------------- Kernel 6: fc3 + quantum kernel head + sigmoid ------------
__global__ void final_kernel(
    const float* __restrict__ h2, const float* __restrict__ w3,
    const float* __restrict__ b3, const float* __restrict__ proto,
    const float* __restrict__ khw, const float* __restrict__ khb,
    float* __restrict__ out) {
  const int m = threadIdx.x;  // 64 lanes
  const float* h = h2 + m * 84;
  float z = b3[0];
  for (int k = 0; k < 84; ++k) z = fmaf(h[k], w3[k], z);
  float logit = khb[0];
#pragma unroll
  for (int p = 0; p < 10; ++p) {
    const float c = cosf((z - proto[p]) * 0.5f);
    const float c2 = c * c;
    logit = fmaf(c2 * c2, khw[p], logit);
  }
  const float pr = 1.0f / (1.0f + expf(-logit));
  out[m * 2 + 0] = pr;
  out[m * 2 + 1] = 1.0f - pr;
}

// ---------------------------------------------------------------------------
extern "C" void kernel_launch(void* const* d_in, const int* in_sizes, int n_in,
                              void* d_out, int out_size, void* d_ws, size_t ws_size,
                              hipStream_t stream) {
  const float* x    = (const float*)d_in[0];
  const float* w1   = (const float*)d_in[1];
  const float* b1   = (const float*)d_in[2];
  const float* w2   = (const float*)d_in[3];
  const float* b2   = (const float*)d_in[4];
  const float* fw1  = (const float*)d_in[5];
  const float* fb1  = (const float*)d_in[6];
  const float* fw2  = (const float*)d_in[7];
  const float* fb2  = (const float*)d_in[8];
  const float* fw3  = (const float*)d_in[9];
  const float* fb3  = (const float*)d_in[10];
  const float* prot = (const float*)d_in[11];
  const float* khw  = (const float*)d_in[12];
  const float* khb  = (const float*)d_in[13];
  float* out = (float*)d_out;

  float* ws = (float*)d_ws;
  // pool1 (dead after conv2) is aliased by fc1 partials (written after).
  float* pool1 = ws;                           // 64*123*123*6 = 5,809,536 f
  float* part  = ws;                           // 219*7680     = 1,681,920 f (alias)
  float* A     = ws + 5809536;                 // 64*55872     = 3,575,808 f
  float* h1    = A + 3575808;                  // 7680 f
  float* h2    = h1 + 7680;                    // 5376 f

  conv1_pool <<<dim3(8, 64), 256, 0, stream>>>(x, w1, b1, pool1);
  conv2_pool <<<dim3(25, 64), 256, 0, stream>>>(pool1, w2, b2, A);
  fc1_partial<<<dim3(NCHUNK), 256, 0, stream>>>(A, fw1, part);
  fc1_reduce <<<dim3(240), 256, 0, stream>>>(part, fb1, h1);
  fc2_kernel <<<dim3(21), 256, 0, stream>>>(h1, fw2, fb2, h2);
  final_kernel<<<dim3(1), 64, 0, stream>>>(h2, fw3, fb3, prot, khw, khb, out);
}